// Round 4
// baseline (3579.573 us; speedup 1.0000x reference)
//
#include <hip/hip_runtime.h>

#define ROWS 32768      // B*T
#define D 512
#define NCODES 8192
#define NSPLIT 4
#define CODES_PER_SPLIT (NCODES / NSPLIT)   // 2048
#define BM 128
#define BN 128
#define BK 32
#define KC 384          // OpenBLAS sgemm kc panel: chain split point

// numpy pairwise f32 sum of squares of a 512-float row:
// ps(512)=ps(256)+ps(256); ps(256)=ps(128)+ps(128); ps(128)=unrolled-8, 8 accs.
__device__ __forceinline__ float np_sumsq_512(const float* __restrict__ p) {
    float blk[4];
#pragma unroll
    for (int b = 0; b < 4; ++b) {
        const float* q = p + b * 128;
        float r[8];
#pragma unroll
        for (int j = 0; j < 8; ++j) r[j] = __fmul_rn(q[j], q[j]);
#pragma unroll
        for (int i = 1; i < 16; ++i)
#pragma unroll
            for (int j = 0; j < 8; ++j)
                r[j] = __fadd_rn(r[j], __fmul_rn(q[i * 8 + j], q[i * 8 + j]));
        blk[b] = __fadd_rn(__fadd_rn(__fadd_rn(r[0], r[1]), __fadd_rn(r[2], r[3])),
                           __fadd_rn(__fadd_rn(r[4], r[5]), __fadd_rn(r[6], r[7])));
    }
    return __fadd_rn(__fadd_rn(blk[0], blk[1]), __fadd_rn(blk[2], blk[3]));
}

// ---------------- kernel 1: row sums of squares ----------------
__global__ void k_rowsums(const float* __restrict__ zE, const float* __restrict__ cb,
                          float* __restrict__ sq, float* __restrict__ e2) {
    int row = blockIdx.x * 64 + threadIdx.x;          // 640 blocks x 64 thr = 40960
    if (row < ROWS) {
        sq[row] = np_sumsq_512(zE + (size_t)row * D);
    } else {
        e2[row - ROWS] = np_sumsq_512(cb + (size_t)(row - ROWS) * D);
    }
}

// ---------------- kernel 2: distance GEMM + fused partial argmin ----------------
// 512 threads, 8x4 micro-tile, dual accumulators replicating OpenBLAS kc=384:
//   m = fl( chain(k=0..383) + chain(k=384..511) ), each chain sequential FMA.
__global__ __launch_bounds__(512)
void k_argmin(const float* __restrict__ zE, const float* __restrict__ cb,
              const float* __restrict__ sq, const float* __restrict__ e2,
              uint2* __restrict__ part) {
    __shared__ float lds[2 * BK * BM];     // 32 KiB
    float* As = lds;
    float* Bs = lds + BK * BM;

    const int cs      = blockIdx.x;
    const int rowBase = blockIdx.y * BM;
    const int tid     = threadIdx.x;
    const int tm      = tid & 15;          // 16 row groups * 8 rows = 128
    const int tn      = tid >> 4;          // 32 col groups * 4 cols = 128
    const int r2      = tid >> 2;          // staging row 0..127
    const int q2      = tid & 3;           // staging k-quarter (8 floats)

    float bv[8];
    int   bi[8];
#pragma unroll
    for (int i = 0; i < 8; ++i) { bv[i] = INFINITY; bi[i] = 0; }

    float srow[8];
#pragma unroll
    for (int i = 0; i < 8; ++i) {
        int rl = (i < 4) ? (tm * 4 + i) : (64 + tm * 4 + (i - 4));
        srow[i] = sq[rowBase + rl];
    }

    for (int ct = 0; ct < CODES_PER_SPLIT / BN; ++ct) {   // 16 code tiles
        const int codeBase = cs * CODES_PER_SPLIT + ct * BN;
        float acc[8][4], m1[8][4];
#pragma unroll
        for (int i = 0; i < 8; ++i)
#pragma unroll
            for (int j = 0; j < 4; ++j) { acc[i][j] = 0.0f; m1[i][j] = 0.0f; }

        for (int ks = 0; ks < D / BK; ++ks) {             // 16 K stages, k ascending
            __syncthreads();
            {
                const float* gA = zE + (size_t)(rowBase + r2) * D + ks * BK + q2 * 8;
                const float* gB = cb + (size_t)(codeBase + r2) * D + ks * BK + q2 * 8;
                float4 va0 = *(const float4*)(gA);
                float4 va1 = *(const float4*)(gA + 4);
                float4 vb0 = *(const float4*)(gB);
                float4 vb1 = *(const float4*)(gB + 4);
                int kk = q2 * 8;
                As[(kk + 0) * BM + r2] = va0.x;  As[(kk + 1) * BM + r2] = va0.y;
                As[(kk + 2) * BM + r2] = va0.z;  As[(kk + 3) * BM + r2] = va0.w;
                As[(kk + 4) * BM + r2] = va1.x;  As[(kk + 5) * BM + r2] = va1.y;
                As[(kk + 6) * BM + r2] = va1.z;  As[(kk + 7) * BM + r2] = va1.w;
                Bs[(kk + 0) * BM + r2] = vb0.x;  Bs[(kk + 1) * BM + r2] = vb0.y;
                Bs[(kk + 2) * BM + r2] = vb0.z;  Bs[(kk + 3) * BM + r2] = vb0.w;
                Bs[(kk + 4) * BM + r2] = vb1.x;  Bs[(kk + 5) * BM + r2] = vb1.y;
                Bs[(kk + 6) * BM + r2] = vb1.z;  Bs[(kk + 7) * BM + r2] = vb1.w;
            }
            __syncthreads();
#pragma unroll 4
            for (int k = 0; k < BK; ++k) {
                float4 a0 = *(const float4*)&As[k * BM + tm * 4];
                float4 a1 = *(const float4*)&As[k * BM + 64 + tm * 4];
                float4 b0 = *(const float4*)&Bs[k * BM + tn * 4];
                float av[8]  = {a0.x, a0.y, a0.z, a0.w, a1.x, a1.y, a1.z, a1.w};
                float bvv[4] = {b0.x, b0.y, b0.z, b0.w};
#pragma unroll
                for (int i = 0; i < 8; ++i)
#pragma unroll
                    for (int j = 0; j < 4; ++j)
                        acc[i][j] = __builtin_fmaf(av[i], bvv[j], acc[i][j]);
            }
            if (ks == KC / BK - 1) {                      // close panel 1 (k=0..383)
#pragma unroll
                for (int i = 0; i < 8; ++i)
#pragma unroll
                    for (int j = 0; j < 4; ++j) { m1[i][j] = acc[i][j]; acc[i][j] = 0.0f; }
            }
        }

        // dist = fl(fl(s - 2*fl(S1+S2)) + e2); ascending code order -> first-min ties
#pragma unroll
        for (int j = 0; j < 4; ++j) {
            int c  = codeBase + tn * 4 + j;
            float ec = e2[c];
#pragma unroll
            for (int i = 0; i < 8; ++i) {
                float m = __fadd_rn(m1[i][j], acc[i][j]);
                float d = __fadd_rn(__fsub_rn(srow[i], __fmul_rn(2.0f, m)), ec);
                if (d < bv[i]) { bv[i] = d; bi[i] = c; }
            }
        }
    }

    __syncthreads();
    float* rv = lds;                        // [128][32]
    int*   ri = (int*)(lds + BM * 32);
#pragma unroll
    for (int i = 0; i < 8; ++i) {
        int rl = (i < 4) ? (tm * 4 + i) : (64 + tm * 4 + (i - 4));
        rv[rl * 32 + tn] = bv[i];
        ri[rl * 32 + tn] = bi[i];
    }
    __syncthreads();
    if (tid < BM) {
        float v = rv[tid * 32];
        int   x = ri[tid * 32];
        for (int t = 1; t < 32; ++t) {
            float v2 = rv[tid * 32 + t];
            int   x2 = ri[tid * 32 + t];
            if (v2 < v || (v2 == v && x2 < x)) { v = v2; x = x2; }
        }
        part[(size_t)(rowBase + tid) * NSPLIT + cs] =
            make_uint2(__float_as_uint(v), (unsigned)x);
    }
}

// ---------------- kernel 3: reduce partials -> ids (f32 output) ----------------
__global__ void k_pick(const uint2* __restrict__ part, int* __restrict__ ids,
                       float* __restrict__ outIds) {
    int rr = blockIdx.x * blockDim.x + threadIdx.x;
    if (rr >= ROWS) return;
    float bvv = __uint_as_float(part[(size_t)rr * NSPLIT].x);
    int   bii = (int)part[(size_t)rr * NSPLIT].y;
    for (int cs2 = 1; cs2 < NSPLIT; ++cs2) {
        float v = __uint_as_float(part[(size_t)rr * NSPLIT + cs2].x);
        int   x = (int)part[(size_t)rr * NSPLIT + cs2].y;
        if (v < bvv || (v == bvv && x < bii)) { bvv = v; bii = x; }
    }
    bii = bii < 0 ? 0 : (bii > NCODES - 1 ? NCODES - 1 : bii);
    ids[rr] = bii;
    outIds[rr] = (float)bii;
}

// ---------------- kernel 4: gather z_q_st (f32) + loss partials ----------------
__global__ void k_gather(const float* __restrict__ zE, const float* __restrict__ cb,
                         const int* __restrict__ ids, float* __restrict__ outZ,
                         double* __restrict__ lossPart) {
    const int tid = threadIdx.x;
    double acc = 0.0;
#pragma unroll
    for (int it = 0; it < 4; ++it) {
        int chunk = blockIdx.x * 256 + tid + it * 1048576;   // float4 chunk id
        int row   = chunk >> 7;
        int koff  = (chunk & 127) << 2;
        int id    = ids[row];
        id = id < 0 ? 0 : (id > NCODES - 1 ? NCODES - 1 : id);
        float4 ze = *(const float4*)(zE + ((size_t)row << 9) + koff);
        float4 zq = *(const float4*)(cb + ((size_t)id << 9) + koff);
        float d0 = __fsub_rn(zq.x, ze.x);
        float d1 = __fsub_rn(zq.y, ze.y);
        float d2 = __fsub_rn(zq.z, ze.z);
        float d3 = __fsub_rn(zq.w, ze.w);
        float4 v;
        v.x = __fadd_rn(ze.x, d0);
        v.y = __fadd_rn(ze.y, d1);
        v.z = __fadd_rn(ze.z, d2);
        v.w = __fadd_rn(ze.w, d3);
        *reinterpret_cast<float4*>(outZ + ((size_t)chunk << 2)) = v;
        acc += (double)d0 * d0 + (double)d1 * d1 + (double)d2 * d2 + (double)d3 * d3;
    }
    for (int off = 32; off; off >>= 1) acc += __shfl_down(acc, off);
    __shared__ double sred[4];
    if ((tid & 63) == 0) sred[tid >> 6] = acc;
    __syncthreads();
    if (tid == 0) lossPart[blockIdx.x] = (sred[0] + sred[1]) + (sred[2] + sred[3]);
}

// ---------------- kernel 5: final loss (f32 output) ----------------
__global__ void k_loss(const double* __restrict__ lossPart, float* __restrict__ outLoss) {
    const int tid = threadIdx.x;
    double acc = 0.0;
    for (int i = tid; i < 4096; i += 256) acc += lossPart[i];
    for (int off = 32; off; off >>= 1) acc += __shfl_down(acc, off);
    __shared__ double sred[4];
    if ((tid & 63) == 0) sred[tid >> 6] = acc;
    __syncthreads();
    if (tid == 0) {
        double mean = ((sred[0] + sred[1]) + (sred[2] + sred[3])) / 16777216.0;
        float cl = (float)mean;
        *outLoss = __fadd_rn(cl, __fmul_rn(0.25f, cl));
    }
}

extern "C" void kernel_launch(void* const* d_in, const int* in_sizes, int n_in,
                              void* d_out, int out_size, void* d_ws, size_t ws_size,
                              hipStream_t stream) {
    (void)in_sizes; (void)n_in; (void)out_size; (void)ws_size;
    const float* zE = (const float*)d_in[0];
    const float* cb = (const float*)d_in[1];
    float* out = (float*)d_out;                    // f32 outputs, concatenated
    char* ws = (char*)d_ws;

    float*  sq       = (float*)(ws + 0);         // 32768 f32
    float*  e2       = (float*)(ws + 131072);    // 8192  f32
    int*    ids      = (int*)(ws + 163840);      // 32768 i32
    uint2*  part     = (uint2*)(ws + 294912);    // 32768*4 uint2 = 1 MiB
    double* lossPart = (double*)(ws + 1343488);  // 4096  f64

    k_rowsums<<<(ROWS + NCODES) / 64, 64, 0, stream>>>(zE, cb, sq, e2);
    dim3 g2(NSPLIT, ROWS / BM);
    k_argmin<<<g2, 512, 0, stream>>>(zE, cb, sq, e2, part);
    k_pick<<<ROWS / 256, 256, 0, stream>>>(part, ids, out + 16777216);
    k_gather<<<4096, 256, 0, stream>>>(zE, cb, ids, out, lossPart);
    k_loss<<<1, 256, 0, stream>>>(lossPart, out + 16777216 + 32768);
}